// Round 10
// baseline (497.711 us; speedup 1.0000x reference)
//
#include <hip/hip_runtime.h>
#include <stdint.h>
#include <stddef.h>

#define DM 1024
#define SEQ 4096
#define NB 4
#define NTOK (NB*SEQ)

typedef __attribute__((ext_vector_type(8))) short s16x8;
typedef __attribute__((ext_vector_type(4))) float f32x4;

__device__ __forceinline__ unsigned short f2bf(float f) {
  unsigned int u = __float_as_uint(f);
  u += 0x7FFFu + ((u >> 16) & 1u);   // round-to-nearest-even
  return (unsigned short)(u >> 16);
}
__device__ __forceinline__ float bf2f(unsigned short u) {
  return __uint_as_float((unsigned int)u << 16);
}

__device__ __forceinline__ f32x4 mfma16(s16x8 a, s16x8 b, f32x4 c) {
  return __builtin_amdgcn_mfma_f32_16x16x32_bf16(a, b, c, 0, 0, 0);
}

__device__ __forceinline__ void gload16(const void* g, void* l) {
  __builtin_amdgcn_global_load_lds((const __attribute__((address_space(1))) unsigned int*)g,
                                   (__attribute__((address_space(3))) unsigned int*)l, 16, 0, 0);
}

// XCD-aware bijective block swizzle (T1). Requires nwg % 8 == 0.
__device__ __forceinline__ void xcd_swz(int gx, int gy, int& x, int& y, int& z) {
  int nwg = gx * gy * gridDim.z;
  int bid = blockIdx.x + gx * (blockIdx.y + gy * blockIdx.z);
  int cpx = nwg >> 3;
  int wg = (bid & 7) * cpx + (bid >> 3);
  x = wg % gx; int t = wg / gx; y = t % gy; z = t / gy;
}

// ---------------- kernel 1: fused f32 -> bf16 convert (x, Wq, Wk, Wv) + lsum zero ----------------
// lsum zeroed IN-KERNEL (hipMemsetAsync is not graph-capture-safe here — R7 failure).
// k_qkv orders between this and k_sgemm on the stream, so zeroing is always visible.
__global__ void k_conv4(const float* __restrict__ x, const float* __restrict__ wq,
                        const float* __restrict__ wk, const float* __restrict__ wv,
                        unsigned short* __restrict__ xb, unsigned short* __restrict__ wb,
                        float* __restrict__ lsum) {
  const int n0 = NTOK * DM / 8;       // 2097152
  const int n1 = DM * DM / 8;         // 131072 (pow2)
  int i0 = blockIdx.x * blockDim.x + threadIdx.x;
  int st = gridDim.x * blockDim.x;
  for (int i = i0; i < NTOK; i += st) lsum[i] = 0.f;
  for (int i = i0; i < n0 + 3 * n1; i += st) {
    const float* s; unsigned short* d; int k;
    if (i < n0) { s = x; d = xb; k = i; }
    else {
      int j = i - n0; int seg = j >> 17; k = j & (n1 - 1);
      s = (seg == 0) ? wq : (seg == 1) ? wk : wv;
      d = wb + (size_t)seg * DM * DM;
    }
    const f32x4* sp = (const f32x4*)s + (size_t)k * 2;
    f32x4 a = sp[0], b = sp[1];
    s16x8 o;
    o[0] = (short)f2bf(a[0]); o[1] = (short)f2bf(a[1]);
    o[2] = (short)f2bf(a[2]); o[3] = (short)f2bf(a[3]);
    o[4] = (short)f2bf(b[0]); o[5] = (short)f2bf(b[1]);
    o[6] = (short)f2bf(b[2]); o[7] = (short)f2bf(b[3]);
    *((s16x8*)d + k) = o;
  }
}

// ---------------- shared GEMM core: C = A @ B^T (both k-major) ----------------
// 128x128 tile, 4 waves, double-buffered LDS (passed from kernel scope so
// multiple instantiations SHARE it). global_load_lds w/ pre-swizzled source.
// EPI: 0 = bf16 + col-bias(aux);  1 = bf16 exp(acc*scale) + fused rowsum atomics(redu);
//      3 = bf16 + row-bias(aux);  4 = f32 / redu[row].
template<int KD, int BK, int EPI>
__device__ __forceinline__ void gemm_core(
    unsigned short (*lds)[2][128 * BK],
    const unsigned short* __restrict__ A, const unsigned short* __restrict__ B,
    void* __restrict__ outp, int ldc, const float* __restrict__ aux, float scale,
    float* __restrict__ redu, int mbase, int nbase)
{
  constexpr int NT     = KD / BK;
  constexpr int SLOTS  = BK / 8;             // 16B slots per row
  constexpr int SMASK  = SLOTS - 1;
  constexpr int PASSES = 128 * SLOTS / 256;  // staging passes per matrix

  const int tid = threadIdx.x, lane = tid & 63, wid = tid >> 6;
  const int wr = wid >> 1, wc = wid & 1;
  const int l15 = lane & 15, lg = lane >> 4;

  f32x4 acc[4][4];
  #pragma unroll
  for (int m = 0; m < 4; m++)
    #pragma unroll
    for (int n = 0; n < 4; n++) { acc[m][n][0]=0.f; acc[m][n][1]=0.f; acc[m][n][2]=0.f; acc[m][n][3]=0.f; }

  auto rswz = [](int row) -> int { return (BK == 64) ? (row & 7) : ((row >> 1) & 3); };

  auto stage = [&](int buf, int kt) {
    const int kb_ = kt * BK;
    #pragma unroll
    for (int p = 0; p < PASSES; p++) {
      int s = p * 256 + tid;
      int row = s / SLOTS, sl = (s & SMASK) ^ rswz(row);
      gload16(A + (size_t)(mbase + row) * KD + kb_ + sl * 8, &lds[buf][0][s * 8]);
    }
    #pragma unroll
    for (int p = 0; p < PASSES; p++) {
      int s = p * 256 + tid;
      int row = s / SLOTS, sl = (s & SMASK) ^ rswz(row);
      gload16(B + (size_t)(nbase + row) * KD + kb_ + sl * 8, &lds[buf][1][s * 8]);
    }
  };

  auto compute = [&](int buf) {
    #pragma unroll
    for (int k2 = 0; k2 < BK / 32; k2++) {
      s16x8 af[4], bf[4];
      #pragma unroll
      for (int m = 0; m < 4; m++) {
        int row = wr * 64 + m * 16 + l15;
        int sl = (k2 * 4 + lg) ^ rswz(row);
        af[m] = *(const s16x8*)(&lds[buf][0][0] + row * BK + sl * 8);
      }
      #pragma unroll
      for (int n = 0; n < 4; n++) {
        int row = wc * 64 + n * 16 + l15;
        int sl = (k2 * 4 + lg) ^ rswz(row);
        bf[n] = *(const s16x8*)(&lds[buf][1][0] + row * BK + sl * 8);
      }
      #pragma unroll
      for (int m = 0; m < 4; m++)
        #pragma unroll
        for (int n = 0; n < 4; n++)
          acc[m][n] = mfma16(af[m], bf[n], acc[m][n]);
    }
  };

  stage(0, 0);
  __syncthreads();
  for (int kt = 0; kt < NT; kt++) {
    int cur = kt & 1;
    if (kt < NT - 1) stage(cur ^ 1, kt + 1);
    compute(cur);
    __syncthreads();
  }

  // --- epilogue ---
  float linv_r[16];
  if (EPI == 4) {
    #pragma unroll
    for (int i = 0; i < 16; i++)
      linv_r[i] = 1.f / redu[mbase + wr * 64 + (i >> 2) * 16 + lg * 4 + (i & 3)];
  }
  float rowpart[16];
  if (EPI == 1) {
    #pragma unroll
    for (int i = 0; i < 16; i++) rowpart[i] = 0.f;
  }

  #pragma unroll
  for (int n = 0; n < 4; n++) {
    int col = nbase + wc * 64 + n * 16 + l15;
    float cb = (EPI == 0) ? aux[col] : 0.f;
    #pragma unroll
    for (int m = 0; m < 4; m++) {
      #pragma unroll
      for (int r = 0; r < 4; r++) {
        int row = mbase + wr * 64 + m * 16 + lg * 4 + r;
        float v = acc[m][n][r];
        if (EPI == 0) {
          ((unsigned short*)outp)[(size_t)row * ldc + col] = f2bf(v + cb);
        } else if (EPI == 1) {
          float e = __expf(v * scale);
          ((unsigned short*)outp)[(size_t)row * ldc + col] = f2bf(e);
          rowpart[m * 4 + r] += e;
        } else if (EPI == 3) {
          ((unsigned short*)outp)[(size_t)row * ldc + col] = f2bf(v + aux[row]);
        } else {
          ((float*)outp)[(size_t)row * ldc + col] = v * linv_r[m * 4 + r];
        }
      }
    }
  }

  if (EPI == 1) {
    #pragma unroll
    for (int i = 0; i < 16; i++) {
      float rs = rowpart[i];
      rs += __shfl_xor(rs, 1); rs += __shfl_xor(rs, 2);
      rs += __shfl_xor(rs, 4); rs += __shfl_xor(rs, 8);
      if (l15 == 0)
        atomicAdd(&redu[mbase + wr * 64 + (i >> 2) * 16 + lg * 4 + (i & 3)], rs);
    }
  }
}

// ---------------- kernel 2: fused QKV projection ----------------
// z=0/1: Q,K = x @ W^T + b.  z=2: VT = Wv @ x^T + bv[row], written transposed.
__global__ __launch_bounds__(256, 4) void k_qkv(
    const unsigned short* __restrict__ xb, const unsigned short* __restrict__ wb,
    const float* __restrict__ b0, const float* __restrict__ b1, const float* __restrict__ bv,
    unsigned short* __restrict__ qo, unsigned short* __restrict__ ko, unsigned short* __restrict__ vt)
{
  __shared__ unsigned short lds[2][2][128 * 32];
  int x, y, z;
  xcd_swz(8, 128, x, y, z);
  if (z < 2) {
    gemm_core<DM, 32, 0>(lds, xb, wb + (size_t)z * DM * DM,
                         z ? ko : qo, DM, z ? b1 : b0, 0.f, nullptr,
                         y * 128, x * 128);
  } else {
    int batch = y >> 5, tokb = (y & 31) * 128;
    gemm_core<DM, 32, 3>(lds, wb + (size_t)2 * DM * DM, xb + (size_t)batch * SEQ * DM,
                         vt + (size_t)batch * DM * SEQ, SEQ, bv, 0.f, nullptr,
                         x * 128, tokb);
  }
}

// ---------------- kernel 4: scores GEMM  E = exp(Q K^T scale) -> bf16, fused rowsum ----------------
__global__ __launch_bounds__(256, 4) void k_sgemm(
    const unsigned short* __restrict__ qb, const unsigned short* __restrict__ kb,
    unsigned short* __restrict__ s0, unsigned short* __restrict__ s1,
    unsigned short* __restrict__ s2, unsigned short* __restrict__ s3,
    float* __restrict__ lsum, int bb)
{
  __shared__ unsigned short lds[2][2][128 * 32];
  int x, y, z;
  xcd_swz(32, 32, x, y, z);
  unsigned short* sc = (z == 0) ? s0 : (z == 1) ? s1 : (z == 2) ? s2 : s3;
  gemm_core<DM, 32, 1>(lds, qb + (size_t)(bb + z) * SEQ * DM, kb + (size_t)(bb + z) * SEQ * DM,
                       sc, SEQ, nullptr, 0.03125f, lsum + (size_t)(bb + z) * SEQ,
                       y * 128, x * 128);
}

// ---------------- kernel 6: O = (E @ V) / lsum[row]  (B-operand = V^T) ----------------
// BK=64: long K-loop (4096 -> 64 iters) amortizes barriers; LDS 64 KB, 2/CU.
__global__ __launch_bounds__(256, 2) void k_pv(
    const unsigned short* __restrict__ s0, const unsigned short* __restrict__ s1,
    const unsigned short* __restrict__ s2, const unsigned short* __restrict__ s3,
    const unsigned short* __restrict__ vt, float* __restrict__ lsum,
    float* __restrict__ out, int bb)
{
  __shared__ unsigned short lds[2][2][128 * 64];
  int x, y, z;
  xcd_swz(8, 32, x, y, z);
  const unsigned short* sc = (z == 0) ? s0 : (z == 1) ? s1 : (z == 2) ? s2 : s3;
  gemm_core<SEQ, 64, 4>(lds, sc, vt + (size_t)(bb + z) * DM * SEQ,
                        out + (size_t)(bb + z) * SEQ * DM, DM,
                        nullptr, 1.f, lsum + (size_t)(bb + z) * SEQ,
                        y * 128, x * 128);
}

extern "C" void kernel_launch(void* const* d_in, const int* in_sizes, int n_in,
                              void* d_out, int out_size, void* d_ws, size_t ws_size,
                              hipStream_t stream) {
  const float* x  = (const float*)d_in[0];
  const float* Wq = (const float*)d_in[1];
  const float* bq = (const float*)d_in[2];
  const float* Wk = (const float*)d_in[3];
  const float* bk = (const float*)d_in[4];
  const float* Wv = (const float*)d_in[5];
  const float* bv = (const float*)d_in[6];
  float* out = (float*)d_out;
  char* ws = (char*)d_ws;

  // ws layout (bytes)
  unsigned short* xb  = (unsigned short*)(ws);              // 32 MB; reused as sc0 after qkv
  unsigned short* wb  = (unsigned short*)(ws + 33554432);   //  6 MB
  unsigned short* qb  = (unsigned short*)(ws + 39845888);   // 32 MB
  unsigned short* kb  = (unsigned short*)(ws + 73400320);   // 32 MB
  unsigned short* sc1 = (unsigned short*)(ws + 106954752);  // 32 MB
  unsigned short* vt  = (unsigned short*)(ws + 140509184);  // 32 MB
  float* lsum         = (float*)(ws + 174063616);           // 64 KB
  unsigned short* sc0 = xb;
  // 4-batch extension (only if workspace is large enough)
  unsigned short* sc2 = (unsigned short*)(ws + 174129152);  // 32 MB
  unsigned short* sc3 = (unsigned short*)(ws + 207683584);  // 32 MB
  const bool big = ws_size >= 241238016ull;                 // ~230 MB

  k_conv4<<<2048, 256, 0, stream>>>(x, Wq, Wk, Wv, xb, wb, lsum);
  k_qkv<<<dim3(8, 128, 3), 256, 0, stream>>>(xb, wb, bq, bk, bv, qb, kb, vt);

  if (big) {
    k_sgemm<<<dim3(32, 32, 4), 256, 0, stream>>>(qb, kb, sc0, sc1, sc2, sc3, lsum, 0);
    k_pv<<<dim3(8, 32, 4), 256, 0, stream>>>(sc0, sc1, sc2, sc3, vt, lsum, out, 0);
  } else {
    for (int bb = 0; bb < NB; bb += 2) {
      k_sgemm<<<dim3(32, 32, 2), 256, 0, stream>>>(qb, kb, sc0, sc1, sc0, sc1, lsum, bb);
      k_pv<<<dim3(8, 32, 2), 256, 0, stream>>>(sc0, sc1, sc0, sc1, vt, lsum, out, bb);
    }
  }
}

// Round 11
// 458.576 us; speedup vs baseline: 1.0853x; 1.0853x over previous
//
#include <hip/hip_runtime.h>
#include <stdint.h>
#include <stddef.h>

#define DM 1024
#define SEQ 4096
#define NB 4
#define NTOK (NB*SEQ)

typedef __attribute__((ext_vector_type(8))) short s16x8;
typedef __attribute__((ext_vector_type(4))) float f32x4;

__device__ __forceinline__ unsigned short f2bf(float f) {
  unsigned int u = __float_as_uint(f);
  u += 0x7FFFu + ((u >> 16) & 1u);   // round-to-nearest-even
  return (unsigned short)(u >> 16);
}
__device__ __forceinline__ float bf2f(unsigned short u) {
  return __uint_as_float((unsigned int)u << 16);
}

__device__ __forceinline__ f32x4 mfma16(s16x8 a, s16x8 b, f32x4 c) {
  return __builtin_amdgcn_mfma_f32_16x16x32_bf16(a, b, c, 0, 0, 0);
}

__device__ __forceinline__ void gload16(const void* g, void* l) {
  __builtin_amdgcn_global_load_lds((const __attribute__((address_space(1))) unsigned int*)g,
                                   (__attribute__((address_space(3))) unsigned int*)l, 16, 0, 0);
}

// XCD-aware bijective block swizzle (T1). Requires nwg % 8 == 0.
__device__ __forceinline__ void xcd_swz(int gx, int gy, int& x, int& y, int& z) {
  int nwg = gx * gy * gridDim.z;
  int bid = blockIdx.x + gx * (blockIdx.y + gy * blockIdx.z);
  int cpx = nwg >> 3;
  int wg = (bid & 7) * cpx + (bid >> 3);
  x = wg % gx; int t = wg / gx; y = t % gy; z = t / gy;
}

// ---------------- kernel 1: fused f32 -> bf16 convert (x, Wq, Wk, Wv) ----------------
__global__ void k_conv4(const float* __restrict__ x, const float* __restrict__ wq,
                        const float* __restrict__ wk, const float* __restrict__ wv,
                        unsigned short* __restrict__ xb, unsigned short* __restrict__ wb) {
  const int n0 = NTOK * DM / 8;       // 2097152
  const int n1 = DM * DM / 8;         // 131072 (pow2)
  int i0 = blockIdx.x * blockDim.x + threadIdx.x;
  int st = gridDim.x * blockDim.x;
  for (int i = i0; i < n0 + 3 * n1; i += st) {
    const float* s; unsigned short* d; int k;
    if (i < n0) { s = x; d = xb; k = i; }
    else {
      int j = i - n0; int seg = j >> 17; k = j & (n1 - 1);
      s = (seg == 0) ? wq : (seg == 1) ? wk : wv;
      d = wb + (size_t)seg * DM * DM;
    }
    const f32x4* sp = (const f32x4*)s + (size_t)k * 2;
    f32x4 a = sp[0], b = sp[1];
    s16x8 o;
    o[0] = (short)f2bf(a[0]); o[1] = (short)f2bf(a[1]);
    o[2] = (short)f2bf(a[2]); o[3] = (short)f2bf(a[3]);
    o[4] = (short)f2bf(b[0]); o[5] = (short)f2bf(b[1]);
    o[6] = (short)f2bf(b[2]); o[7] = (short)f2bf(b[3]);
    *((s16x8*)d + k) = o;
  }
}

// ---------------- shared GEMM core: C = A @ B^T (both k-major) ----------------
// 128x128 tile, 4 waves, double-buffered LDS (passed from kernel scope so
// multiple instantiations SHARE it). global_load_lds w/ pre-swizzled source.
// EPI: 0 = bf16 + col-bias(aux);  1 = bf16 exp(acc*scale);
//      3 = bf16 + row-bias(aux);  4 = f32 * row-scale(aux).
template<int KD, int BK, int EPI>
__device__ __forceinline__ void gemm_core(
    unsigned short (*lds)[2][128 * BK],
    const unsigned short* __restrict__ A, const unsigned short* __restrict__ B,
    void* __restrict__ outp, int ldc, const float* __restrict__ aux, float scale,
    int mbase, int nbase)
{
  constexpr int NT     = KD / BK;
  constexpr int SLOTS  = BK / 8;             // 16B slots per row
  constexpr int SMASK  = SLOTS - 1;
  constexpr int PASSES = 128 * SLOTS / 256;  // staging passes per matrix

  const int tid = threadIdx.x, lane = tid & 63, wid = tid >> 6;
  const int wr = wid >> 1, wc = wid & 1;
  const int l15 = lane & 15, lg = lane >> 4;

  f32x4 acc[4][4];
  #pragma unroll
  for (int m = 0; m < 4; m++)
    #pragma unroll
    for (int n = 0; n < 4; n++) { acc[m][n][0]=0.f; acc[m][n][1]=0.f; acc[m][n][2]=0.f; acc[m][n][3]=0.f; }

  auto rswz = [](int row) -> int { return (BK == 64) ? (row & 7) : ((row >> 1) & 3); };

  auto stage = [&](int buf, int kt) {
    const int kb_ = kt * BK;
    #pragma unroll
    for (int p = 0; p < PASSES; p++) {
      int s = p * 256 + tid;
      int row = s / SLOTS, sl = (s & SMASK) ^ rswz(row);
      gload16(A + (size_t)(mbase + row) * KD + kb_ + sl * 8, &lds[buf][0][s * 8]);
    }
    #pragma unroll
    for (int p = 0; p < PASSES; p++) {
      int s = p * 256 + tid;
      int row = s / SLOTS, sl = (s & SMASK) ^ rswz(row);
      gload16(B + (size_t)(nbase + row) * KD + kb_ + sl * 8, &lds[buf][1][s * 8]);
    }
  };

  auto compute = [&](int buf) {
    #pragma unroll
    for (int k2 = 0; k2 < BK / 32; k2++) {
      s16x8 af[4], bf[4];
      #pragma unroll
      for (int m = 0; m < 4; m++) {
        int row = wr * 64 + m * 16 + l15;
        int sl = (k2 * 4 + lg) ^ rswz(row);
        af[m] = *(const s16x8*)(&lds[buf][0][0] + row * BK + sl * 8);
      }
      #pragma unroll
      for (int n = 0; n < 4; n++) {
        int row = wc * 64 + n * 16 + l15;
        int sl = (k2 * 4 + lg) ^ rswz(row);
        bf[n] = *(const s16x8*)(&lds[buf][1][0] + row * BK + sl * 8);
      }
      #pragma unroll
      for (int m = 0; m < 4; m++)
        #pragma unroll
        for (int n = 0; n < 4; n++)
          acc[m][n] = mfma16(af[m], bf[n], acc[m][n]);
    }
  };

  stage(0, 0);
  __syncthreads();
  for (int kt = 0; kt < NT; kt++) {
    int cur = kt & 1;
    if (kt < NT - 1) stage(cur ^ 1, kt + 1);
    compute(cur);
    __syncthreads();
  }

  #pragma unroll
  for (int n = 0; n < 4; n++) {
    int col = nbase + wc * 64 + n * 16 + l15;
    float cb = (EPI == 0) ? aux[col] : 0.f;
    #pragma unroll
    for (int m = 0; m < 4; m++) {
      #pragma unroll
      for (int r = 0; r < 4; r++) {
        int row = mbase + wr * 64 + m * 16 + lg * 4 + r;
        float v = acc[m][n][r];
        if (EPI == 0) {
          ((unsigned short*)outp)[(size_t)row * ldc + col] = f2bf(v + cb);
        } else if (EPI == 1) {
          ((unsigned short*)outp)[(size_t)row * ldc + col] = f2bf(__expf(v * scale));
        } else if (EPI == 3) {
          ((unsigned short*)outp)[(size_t)row * ldc + col] = f2bf(v + aux[row]);
        } else {
          ((float*)outp)[(size_t)row * ldc + col] = v * aux[row];
        }
      }
    }
  }
}

// ---------------- kernel 2: fused QKV projection ----------------
// z=0/1: Q,K = x @ W^T + b.  z=2: VT = Wv @ x^T + bv[row], written transposed.
__global__ __launch_bounds__(256, 4) void k_qkv(
    const unsigned short* __restrict__ xb, const unsigned short* __restrict__ wb,
    const float* __restrict__ b0, const float* __restrict__ b1, const float* __restrict__ bv,
    unsigned short* __restrict__ qo, unsigned short* __restrict__ ko, unsigned short* __restrict__ vt)
{
  __shared__ unsigned short lds[2][2][128 * 32];
  int x, y, z;
  xcd_swz(8, 128, x, y, z);
  if (z < 2) {
    gemm_core<DM, 32, 0>(lds, xb, wb + (size_t)z * DM * DM,
                         z ? ko : qo, DM, z ? b1 : b0, 0.f,
                         y * 128, x * 128);
  } else {
    int batch = y >> 5, tokb = (y & 31) * 128;
    gemm_core<DM, 32, 3>(lds, wb + (size_t)2 * DM * DM, xb + (size_t)batch * SEQ * DM,
                         vt + (size_t)batch * DM * SEQ, SEQ, bv, 0.f,
                         x * 128, tokb);
  }
}

// ---------------- kernel 4: scores GEMM  E = exp(Q K^T scale) -> bf16 ----------------
// Chunked XCD mapping: each XCD owns a 16y x 32x half-batch region traversed in
// four (16y x 8x) chunks -> K-panel working set 2 MB + Q 4 MB ~ L2-resident,
// vs the plain swizzle's 8 MB K stream that thrashed L2 (FETCH 424 MB).
__global__ __launch_bounds__(256, 4) void k_sgemm(
    const unsigned short* __restrict__ qb, const unsigned short* __restrict__ kb,
    unsigned short* __restrict__ s0, unsigned short* __restrict__ s1,
    unsigned short* __restrict__ s2, unsigned short* __restrict__ s3, int bb)
{
  __shared__ unsigned short lds[2][2][128 * 32];
  int bid = blockIdx.x + 32 * (blockIdx.y + 32 * blockIdx.z);
  int xcd = bid & 7, wg = bid >> 3;
  int x, y, z;
  if (gridDim.z == 4) {
    // 4096 wgs: XCD owns z=xcd>>1, 16-row slab, 4 chunks of 16y x 8x
    z = xcd >> 1;
    int y0 = (xcd & 1) << 4;
    int xc = wg >> 7, r = wg & 127;
    x = xc * 8 + (r & 7);
    y = y0 + (r >> 3);
  } else {
    // 2048 wgs: XCD owns z=xcd>>2, 8-row slab, 4 chunks of 8y x 8x
    z = xcd >> 2;
    int y0 = (xcd & 3) << 3;
    int xc = wg >> 6, r = wg & 63;
    x = xc * 8 + (r & 7);
    y = y0 + (r >> 3);
  }
  unsigned short* sc = (z == 0) ? s0 : (z == 1) ? s1 : (z == 2) ? s2 : s3;
  gemm_core<DM, 32, 1>(lds, qb + (size_t)(bb + z) * SEQ * DM, kb + (size_t)(bb + z) * SEQ * DM,
                       sc, SEQ, nullptr, 0.03125f,
                       y * 128, x * 128);
}

// ---------------- kernel 5: row-sum of E -> 1/l ----------------
__global__ __launch_bounds__(256) void k_rowsum(
    const unsigned short* __restrict__ s0, const unsigned short* __restrict__ s1,
    const unsigned short* __restrict__ s2, const unsigned short* __restrict__ s3,
    float* __restrict__ linv, int bb) {
  const int z = blockIdx.z;
  const unsigned short* sc = (z == 0) ? s0 : (z == 1) ? s1 : (z == 2) ? s2 : s3;
  const int row = blockIdx.x * 4 + (threadIdx.x >> 6);
  const int lane = threadIdx.x & 63;
  const unsigned short* rp = sc + (size_t)row * SEQ + lane * 8;
  float s = 0.f;
  #pragma unroll
  for (int j = 0; j < 8; j++) {
    s16x8 v = *(const s16x8*)(rp + (size_t)j * 512);
    #pragma unroll
    for (int t = 0; t < 8; t++) s += bf2f((unsigned short)v[t]);
  }
  s += __shfl_xor(s, 1);  s += __shfl_xor(s, 2);  s += __shfl_xor(s, 4);
  s += __shfl_xor(s, 8);  s += __shfl_xor(s, 16); s += __shfl_xor(s, 32);
  if (lane == 0) linv[(size_t)(bb + z) * SEQ + row] = 1.f / s;
}

// ---------------- kernel 6: O = (E @ V) * linv[row]  (B-operand = V^T) ----------------
// BK=64: long K-loop (4096 -> 64 iters) amortizes barriers; LDS 64 KB, 2/CU.
__global__ __launch_bounds__(256, 2) void k_pv(
    const unsigned short* __restrict__ s0, const unsigned short* __restrict__ s1,
    const unsigned short* __restrict__ s2, const unsigned short* __restrict__ s3,
    const unsigned short* __restrict__ vt, const float* __restrict__ linv,
    float* __restrict__ out, int bb)
{
  __shared__ unsigned short lds[2][2][128 * 64];
  int x, y, z;
  xcd_swz(8, 32, x, y, z);
  const unsigned short* sc = (z == 0) ? s0 : (z == 1) ? s1 : (z == 2) ? s2 : s3;
  gemm_core<SEQ, 64, 4>(lds, sc, vt + (size_t)(bb + z) * DM * SEQ,
                        out + (size_t)(bb + z) * SEQ * DM, DM,
                        linv + (size_t)(bb + z) * SEQ, 1.f,
                        y * 128, x * 128);
}

extern "C" void kernel_launch(void* const* d_in, const int* in_sizes, int n_in,
                              void* d_out, int out_size, void* d_ws, size_t ws_size,
                              hipStream_t stream) {
  const float* x  = (const float*)d_in[0];
  const float* Wq = (const float*)d_in[1];
  const float* bq = (const float*)d_in[2];
  const float* Wk = (const float*)d_in[3];
  const float* bk = (const float*)d_in[4];
  const float* Wv = (const float*)d_in[5];
  const float* bv = (const float*)d_in[6];
  float* out = (float*)d_out;
  char* ws = (char*)d_ws;

  // ws layout (bytes)
  unsigned short* xb  = (unsigned short*)(ws);              // 32 MB; reused as sc0 after qkv
  unsigned short* wb  = (unsigned short*)(ws + 33554432);   //  6 MB
  unsigned short* qb  = (unsigned short*)(ws + 39845888);   // 32 MB
  unsigned short* kb  = (unsigned short*)(ws + 73400320);   // 32 MB
  unsigned short* sc1 = (unsigned short*)(ws + 106954752);  // 32 MB
  unsigned short* vt  = (unsigned short*)(ws + 140509184);  // 32 MB
  float* linv         = (float*)(ws + 174063616);           // 64 KB
  unsigned short* sc0 = xb;
  // 4-batch extension (only if workspace is large enough)
  unsigned short* sc2 = (unsigned short*)(ws + 174129152);  // 32 MB
  unsigned short* sc3 = (unsigned short*)(ws + 207683584);  // 32 MB
  const bool big = ws_size >= 241238016ull;                 // ~230 MB

  k_conv4<<<2048, 256, 0, stream>>>(x, Wq, Wk, Wv, xb, wb);
  k_qkv<<<dim3(8, 128, 3), 256, 0, stream>>>(xb, wb, bq, bk, bv, qb, kb, vt);

  if (big) {
    k_sgemm<<<dim3(32, 32, 4), 256, 0, stream>>>(qb, kb, sc0, sc1, sc2, sc3, 0);
    k_rowsum<<<dim3(1024, 1, 4), 256, 0, stream>>>(sc0, sc1, sc2, sc3, linv, 0);
    k_pv<<<dim3(8, 32, 4), 256, 0, stream>>>(sc0, sc1, sc2, sc3, vt, linv, out, 0);
  } else {
    for (int bb = 0; bb < NB; bb += 2) {
      k_sgemm<<<dim3(32, 32, 2), 256, 0, stream>>>(qb, kb, sc0, sc1, sc0, sc1, bb);
      k_rowsum<<<dim3(1024, 1, 2), 256, 0, stream>>>(sc0, sc1, sc0, sc1, linv, bb);
      k_pv<<<dim3(8, 32, 2), 256, 0, stream>>>(sc0, sc1, sc0, sc1, vt, linv, out, bb);
    }
  }
}